// Round 11
// baseline (175.750 us; speedup 1.0000x reference)
//
#include <hip/hip_runtime.h>
#include <math.h>

#define BB 8
#define CC 64
#define OO 64
#define HH 128
#define WW 128
#define HW (HH*WW)              // 16384
#define NPIX (BB*HW)            // 131072

typedef __bf16 bf16x8 __attribute__((ext_vector_type(8)));
typedef float floatx4 __attribute__((ext_vector_type(4)));
typedef float f32x2 __attribute__((ext_vector_type(2)));
typedef unsigned short ushort_t;

// Workspace layout (bytes):
//  xt : bf16 NHWC [B][H][W][64]        16777216
//  om : fp32 [NPIX][28]                14680064
//  wt : bf16 [64][576]  (o, tap*64+c)     73728
//  wb : bf16 [32][576]  (o27pad, k)       36864
#define XT_BYTES  16777216
#define OM_BYTES  14680064
#define WT_BYTES  73728

__device__ __forceinline__ unsigned short f2b(float f) {
    unsigned u = __float_as_uint(f);
    u += 0x7fffu + ((u >> 16) & 1u);       // round-to-nearest-even
    return (unsigned short)(u >> 16);
}

// packed 2xf32 -> 2xbf16 in one VALU op (no builtin on gfx950; asm per guide)
__device__ __forceinline__ unsigned cvt_pk_bf16(float lo, float hi) {
    unsigned r;
    asm("v_cvt_pk_bf16_f32 %0, %1, %2" : "=v"(r) : "v"(lo), "v"(hi));
    return r;
}

__device__ __forceinline__ f32x2 pk_fma(f32x2 a, f32x2 b, f32x2 c) {
    f32x2 d;
    asm("v_pk_fma_f32 %0, %1, %2, %3" : "=v"(d) : "v"(a), "v"(b), "v"(c));
    return d;
}

__device__ __forceinline__ f32x2 pk_mul(f32x2 a, f32x2 b) {
    f32x2 d;
    asm("v_pk_mul_f32 %0, %1, %2" : "=v"(d) : "v"(a), "v"(b));
    return d;
}

// ---------------------------------------------------------------------------
// Kernel 1: FUSED prep — transpose (blocks 0..4095) + weight repack (4096..)
// Vectorized loads (2x float4) and stores (uint4 = 8 bf16 ch).
// ---------------------------------------------------------------------------
__global__ __launch_bounds__(256) void prep_kernel(
    const float* __restrict__ x,
    const float* __restrict__ wm, const float* __restrict__ woff,
    const float* __restrict__ wmask,
    ushort_t* __restrict__ xt, ushort_t* __restrict__ wt,
    ushort_t* __restrict__ wb)
{
    __shared__ float tile[64][33];
    int bid = blockIdx.x;
    int t   = threadIdx.x;

    if (bid < 4096) {
        // ---- transpose: NCHW fp32 -> NHWC bf16 ----
        int bh = bid >> 2;
        int w0 = (bid & 3) * 32;
        int b  = bh >> 7;
        int h  = bh & 127;

        {
            int c  = t >> 2;
            int wq = t & 3;
            const float* src = x + (((size_t)(b*CC + c))*HH + h)*WW + (w0 + wq*8);
            float4 v0 = ((const float4*)src)[0];
            float4 v1 = ((const float4*)src)[1];
            int wbse = wq*8;
            tile[c][wbse+0] = v0.x; tile[c][wbse+1] = v0.y;
            tile[c][wbse+2] = v0.z; tile[c][wbse+3] = v0.w;
            tile[c][wbse+4] = v1.x; tile[c][wbse+5] = v1.y;
            tile[c][wbse+6] = v1.z; tile[c][wbse+7] = v1.w;
        }
        __syncthreads();
        {
            int w   = t & 31;
            int cg8 = t >> 5;
            unsigned uu[4];
            #pragma unroll
            for (int j = 0; j < 4; ++j)
                uu[j] = cvt_pk_bf16(tile[cg8*8 + 2*j][w], tile[cg8*8 + 2*j + 1][w]);
            *(uint4*)(xt + (((size_t)(b*HH + h))*WW + (w0 + w))*CC + cg8*8)
                = make_uint4(uu[0], uu[1], uu[2], uu[3]);
        }
    } else {
        // ---- weight repack to bf16 ----
        int i = (bid - 4096) * 256 + t;
        if (i < 36864) {
            int o = i / 576, k = i % 576, tap = k >> 6, c = k & 63;
            wt[i] = f2b(wm[o*576 + c*9 + tap]);
        }
        int j = i - 36864;
        if (j >= 0 && j < 18432) {
            int o = j / 576, k = j % 576, tap = k >> 6, c = k & 63;
            float v = 0.f;
            if (o < 18)      v = woff[o*576 + c*9 + tap];
            else if (o < 27) v = wmask[(o-18)*576 + c*9 + tap];
            wb[j] = f2b(v);
        }
    }
}

// ---------------------------------------------------------------------------
// Kernel 2: conv3x3 -> 18 offsets + 9 sigmoid masks (r5 form, 16x16 tiles).
// Separate kernel on purpose: runs at its own occupancy instead of being
// serialized inside deform blocks (fusion measured ~7us worse overall).
// ---------------------------------------------------------------------------
__global__ __launch_bounds__(256) void conv27_kernel(
    const ushort_t* __restrict__ xt, const ushort_t* __restrict__ wb,
    const float* __restrict__ boff, const float* __restrict__ bmsk,
    float* __restrict__ om)
{
    __shared__ ushort_t win[18*18*72];
    int bid = blockIdx.x;
    int b  = bid >> 6;
    int th = (bid >> 3) & 7;
    int tw = bid & 7;
    int h0 = th * 16, w0 = tw * 16;
    int t = threadIdx.x;

    for (int idx = t; idx < 18*18*8; idx += 256) {
        int r   = idx / 144;
        int rem = idx - r*144;
        int col = rem >> 3;
        int ch  = (rem & 7) << 3;
        int y = h0 + r - 1, x = w0 + col - 1;
        uint4 val = make_uint4(0,0,0,0);
        if ((unsigned)y < (unsigned)HH && (unsigned)x < (unsigned)WW)
            val = *(const uint4*)(xt + ((((size_t)b*HH + y)*WW + x) << 6) + ch);
        *(uint4*)(win + (r*18 + col)*72 + ch) = val;
    }
    __syncthreads();

    int lane = t & 63, wv = t >> 6;
    int n = lane & 15, quad = lane >> 4;
    const ushort_t* wb0 = wb + n*576;
    const ushort_t* wb1 = wb + (16 + n)*576;

    floatx4 acc0[4], acc1[4];
    #pragma unroll
    for (int mt = 0; mt < 4; ++mt) {
        acc0[mt] = (floatx4){0.f,0.f,0.f,0.f};
        acc1[mt] = (floatx4){0.f,0.f,0.f,0.f};
    }

    #pragma unroll
    for (int s = 0; s < 18; ++s) {
        int tap  = s >> 1;
        int tr   = tap / 3, tc = tap % 3;
        int coff = (s & 1)*32 + quad*8;
        int kk = tap*64 + coff;
        bf16x8 b0 = *(const bf16x8*)(wb0 + kk);
        bf16x8 b1 = *(const bf16x8*)(wb1 + kk);
        #pragma unroll
        for (int mt = 0; mt < 4; ++mt) {
            int ty = wv*4 + mt;
            bf16x8 a = *(const bf16x8*)(win + ((ty + tr)*18 + (n + tc))*72 + coff);
            acc0[mt] = __builtin_amdgcn_mfma_f32_16x16x32_bf16(a, b0, acc0[mt], 0, 0, 0);
            acc1[mt] = __builtin_amdgcn_mfma_f32_16x16x32_bf16(a, b1, acc1[mt], 0, 0, 0);
        }
    }

    #pragma unroll
    for (int mt = 0; mt < 4; ++mt) {
        int ty = wv*4 + mt;
        #pragma unroll
        for (int r = 0; r < 4; ++r) {
            int tx = quad*4 + r;
            size_t p = ((size_t)(b*HH + h0 + ty))*WW + (w0 + tx);
            float* dst = om + p*28;
            dst[n] = acc0[mt][r] + boff[n];
            int o1 = 16 + n;
            if (o1 < 18) {
                dst[o1] = acc1[mt][r] + boff[o1];
            } else if (o1 < 27) {
                float z = acc1[mt][r] + bmsk[o1 - 18];
                dst[o1] = 1.f / (1.f + expf(-z));
            } else if (o1 == 27) {
                dst[27] = 0.f;
            }
        }
    }
}

// ---------------------------------------------------------------------------
// Kernel 3: deformable sampling + bf16 MFMA GEMM — 3-tap phased + T14
// async-stage: phase p+1's 24 gathers are ISSUED right after phase p's
// ds_writes, and CONSUMED (pack) at the top of phase p+1 — their latency
// lands under the barrier + 24-MFMA block instead of stalling phase A.
// All 9 taps' addresses derive from om params available up front.
// setprio(1) around the MFMA cluster (waves at different phases across
// blocks — the T5-favorable regime).
// ---------------------------------------------------------------------------
#define SROW 200   // ushorts per pixel row: 3 taps * 64 ch + 8 pad

__global__ __launch_bounds__(256, 3) void deform_kernel(
    const ushort_t* __restrict__ xt, const float* __restrict__ om,
    const ushort_t* __restrict__ wt, float* __restrict__ out)
{
    __shared__ ushort_t samp[64*SROW];   // 25600 B, single-buffered

    int t = threadIdx.x;
    int lane = t & 63, wv = t >> 6;
    int bid = blockIdx.x;
    int b  = bid >> 8;
    int th = (bid >> 4) & 15;
    int tw = bid & 15;
    int h0 = th * 8, w0 = tw * 8;

    // sampling role: 4 threads/pixel, 16 ch each; 8x8 pixel tile
    int pa = t >> 2, cg = t & 3;
    int ph = pa >> 3, pw = pa & 7;
    int h_a = h0 + ph, w_a = w0 + pw;
    const float* omp = om + (((size_t)(b*HH + h_a))*WW + w_a) * 28;
    const ushort_t* xbase = xt + ((size_t)b << 20);

    // MFMA role
    int n = lane & 15, quad = lane >> 4;
    floatx4 acc[4];
    #pragma unroll
    for (int i = 0; i < 4; ++i) acc[i] = (floatx4){0.f,0.f,0.f,0.f};
    const ushort_t* wrow = wt + (wv*16 + n)*576 + quad*8;

    uint4 q[24];     // in-flight gathers for one phase (96 VGPR)
    float cwv[12];   // 4 corner weights x 3 taps for the in-flight phase

    // issue all gathers + compute corner weights for phase pp
    auto issue_phase = [&](int pp, const float* dy3, const float* dx3,
                           const float* m3) {
        #pragma unroll
        for (int kk = 0; kk < 3; ++kk) {
            float py = (float)(h_a + pp - 1) + dy3[kk];
            float px = (float)(w_a + kk - 1) + dx3[kk];
            float y0f = floorf(py), x0f = floorf(px);
            float ly = py - y0f, lx = px - x0f;
            int y0 = (int)y0f, x0 = (int)x0f, y1 = y0 + 1, x1 = x0 + 1;
            float vy0 = ((unsigned)y0 < (unsigned)HH) ? 1.f : 0.f;
            float vy1 = ((unsigned)y1 < (unsigned)HH) ? 1.f : 0.f;
            float vx0 = ((unsigned)x0 < (unsigned)WW) ? 1.f : 0.f;
            float vx1 = ((unsigned)x1 < (unsigned)WW) ? 1.f : 0.f;
            float m   = m3[kk];
            cwv[kk*4+0] = (1.f-ly)*(1.f-lx)*vy0*vx0*m;
            cwv[kk*4+1] = (1.f-ly)*lx      *vy0*vx1*m;
            cwv[kk*4+2] = ly*(1.f-lx)      *vy1*vx0*m;
            cwv[kk*4+3] = ly*lx            *vy1*vx1*m;
            int ys[4] = { y0, y0, y1, y1 };
            int xs[4] = { x0, x1, x0, x1 };
            #pragma unroll
            for (int cn = 0; cn < 4; ++cn) {
                int yc = min(max(ys[cn], 0), HH-1);
                int xc = min(max(xs[cn], 0), WW-1);
                const uint4* cp = (const uint4*)(xbase + (((yc << 7) + xc) << 6) + cg*16);
                q[kk*8+2*cn]   = cp[0];
                q[kk*8+2*cn+1] = cp[1];
            }
        }
    };

    // params + issue for phase 0
    float dyv[3], dxv[3], mv[3];
    #pragma unroll
    for (int j = 0; j < 3; ++j) {
        dyv[j] = omp[2*j]; dxv[j] = omp[2*j+1]; mv[j] = omp[18+j];
    }
    issue_phase(0, dyv, dxv, mv);

    #pragma unroll
    for (int p = 0; p < 3; ++p) {
        // this phase's 6 weight B-frags (L1/L2-hot 73KB table)
        bf16x8 wf[6];
        #pragma unroll
        for (int s = 0; s < 6; ++s)
            wf[s] = *(const bf16x8*)(wrow + (p*6 + s)*32);   // tap*64+half*32

        // next phase's params
        float dyn_[3], dxn_[3], mn_[3];
        if (p < 2) {
            #pragma unroll
            for (int j = 0; j < 3; ++j) {
                int k2 = 3*(p+1) + j;
                dyn_[j] = omp[2*k2]; dxn_[j] = omp[2*k2+1]; mn_[j] = omp[18+k2];
            }
        }

        if (p) __syncthreads();   // WAR: previous phase's MFMA reads complete

        // pack + write this phase (q filled one phase ago; waitcnt here)
        #pragma unroll
        for (int kk = 0; kk < 3; ++kk) {
            f32x2 v2[8];
            {
                f32x2 w2; w2.x = cwv[kk*4+0]; w2.y = cwv[kk*4+0];
                unsigned u0[8] = { q[kk*8+0].x, q[kk*8+0].y, q[kk*8+0].z, q[kk*8+0].w,
                                   q[kk*8+1].x, q[kk*8+1].y, q[kk*8+1].z, q[kk*8+1].w };
                #pragma unroll
                for (int j = 0; j < 8; ++j) {
                    f32x2 f;
                    f.x = __uint_as_float(u0[j] << 16);
                    f.y = __uint_as_float(u0[j] & 0xffff0000u);
                    v2[j] = pk_mul(f, w2);
                }
            }
            #pragma unroll
            for (int cn = 1; cn < 4; ++cn) {
                f32x2 w2; w2.x = cwv[kk*4+cn]; w2.y = cwv[kk*4+cn];
                unsigned u0[8] = { q[kk*8+2*cn].x,   q[kk*8+2*cn].y,
                                   q[kk*8+2*cn].z,   q[kk*8+2*cn].w,
                                   q[kk*8+2*cn+1].x, q[kk*8+2*cn+1].y,
                                   q[kk*8+2*cn+1].z, q[kk*8+2*cn+1].w };
                #pragma unroll
                for (int j = 0; j < 8; ++j) {
                    f32x2 f;
                    f.x = __uint_as_float(u0[j] << 16);
                    f.y = __uint_as_float(u0[j] & 0xffff0000u);
                    v2[j] = pk_fma(f, w2, v2[j]);
                }
            }
            unsigned uu[8];
            #pragma unroll
            for (int j = 0; j < 8; ++j)
                uu[j] = cvt_pk_bf16(v2[j].x, v2[j].y);
            uint4* dst = (uint4*)(samp + pa*SROW + kk*64 + cg*16);
            dst[0] = make_uint4(uu[0], uu[1], uu[2], uu[3]);
            dst[1] = make_uint4(uu[4], uu[5], uu[6], uu[7]);
        }

        // T14: issue next phase's 24 gathers NOW — latency hides under the
        // barrier + MFMA block below.
        if (p < 2) issue_phase(p+1, dyn_, dxn_, mn_);

        __syncthreads();          // RAW: samp ready

        // ---------------- 24 MFMAs from LDS + reg weights ----------------
        __builtin_amdgcn_s_setprio(1);
        #pragma unroll
        for (int kk = 0; kk < 3; ++kk) {
            #pragma unroll
            for (int half = 0; half < 2; ++half) {
                bf16x8 bfrag = wf[kk*2 + half];
                #pragma unroll
                for (int mt = 0; mt < 4; ++mt) {
                    bf16x8 afrag = *(const bf16x8*)(samp + (mt*16 + n)*SROW
                                                    + kk*64 + half*32 + quad*8);
                    acc[mt] = __builtin_amdgcn_mfma_f32_16x16x32_bf16(
                                  afrag, bfrag, acc[mt], 0, 0, 0);
                }
            }
        }
        __builtin_amdgcn_s_setprio(0);
    }

    // store: out[b][o][h][w], o = wv*16 + n; D rows = local pixel id
    // p_local = mt*16 + quad*4 + r -> row = h0 + mt*2 + (quad>>1),
    //                                  col = w0 + (quad&1)*4 + r
    float* op = out + ((size_t)b*OO + (wv*16 + n))*HW;
    #pragma unroll
    for (int mt = 0; mt < 4; ++mt) {
        int row = h0 + mt*2 + (quad >> 1);
        int col = w0 + (quad & 1)*4;
        float4 st = make_float4(acc[mt][0], acc[mt][1], acc[mt][2], acc[mt][3]);
        *(float4*)(op + row*WW + col) = st;
    }
}

// ---------------------------------------------------------------------------
extern "C" void kernel_launch(void* const* d_in, const int* in_sizes, int n_in,
                              void* d_out, int out_size, void* d_ws, size_t ws_size,
                              hipStream_t stream)
{
    const float* x      = (const float*)d_in[0];
    const float* w_main = (const float*)d_in[1];
    const float* w_off  = (const float*)d_in[2];
    const float* b_off  = (const float*)d_in[3];
    const float* w_msk  = (const float*)d_in[4];
    const float* b_msk  = (const float*)d_in[5];
    float* out = (float*)d_out;

    unsigned char* ws = (unsigned char*)d_ws;
    ushort_t* xt = (ushort_t*)ws;
    float*    om = (float*)(ws + XT_BYTES);
    ushort_t* wt = (ushort_t*)(ws + XT_BYTES + OM_BYTES);
    ushort_t* wb = (ushort_t*)(ws + XT_BYTES + OM_BYTES + WT_BYTES);

    // K1: transpose (4096 blocks) + repack (216 blocks) fused
    prep_kernel<<<4096 + 216, 256, 0, stream>>>(x, w_main, w_off, w_msk, xt, wt, wb);

    // K2: conv27 (r5 form, own occupancy)
    conv27_kernel<<<NPIX/256, 256, 0, stream>>>(xt, wb, b_off, b_msk, om);

    // K3: deform, 3-tap phased + async-stage prefetch
    deform_kernel<<<NPIX/64, 256, 0, stream>>>(xt, om, wt, out);
}

// Round 12
// 158.025 us; speedup vs baseline: 1.1122x; 1.1122x over previous
//
#include <hip/hip_runtime.h>
#include <math.h>

#define BB 8
#define CC 64
#define OO 64
#define HH 128
#define WW 128
#define HW (HH*WW)              // 16384
#define NPIX (BB*HW)            // 131072

typedef __bf16 bf16x8 __attribute__((ext_vector_type(8)));
typedef float floatx4 __attribute__((ext_vector_type(4)));
typedef float f32x2 __attribute__((ext_vector_type(2)));
typedef unsigned short ushort_t;

// Workspace layout (bytes):
//  xt : bf16 NHWC [B][H][W][64]        16777216
//  om : fp32 [NPIX][28]                14680064
//  wt : bf16 [64][576]  (o, tap*64+c)     73728
//  wb : bf16 [32][576]  (o27pad, k)       36864
#define XT_BYTES  16777216
#define OM_BYTES  14680064
#define WT_BYTES  73728

__device__ __forceinline__ unsigned short f2b(float f) {
    unsigned u = __float_as_uint(f);
    u += 0x7fffu + ((u >> 16) & 1u);       // round-to-nearest-even
    return (unsigned short)(u >> 16);
}

// packed 2xf32 -> 2xbf16 in one VALU op (no builtin on gfx950; asm per guide)
__device__ __forceinline__ unsigned cvt_pk_bf16(float lo, float hi) {
    unsigned r;
    asm("v_cvt_pk_bf16_f32 %0, %1, %2" : "=v"(r) : "v"(lo), "v"(hi));
    return r;
}

__device__ __forceinline__ f32x2 pk_fma(f32x2 a, f32x2 b, f32x2 c) {
    f32x2 d;
    asm("v_pk_fma_f32 %0, %1, %2, %3" : "=v"(d) : "v"(a), "v"(b), "v"(c));
    return d;
}

__device__ __forceinline__ f32x2 pk_mul(f32x2 a, f32x2 b) {
    f32x2 d;
    asm("v_pk_mul_f32 %0, %1, %2" : "=v"(d) : "v"(a), "v"(b));
    return d;
}

// ---------------------------------------------------------------------------
// Kernel 1: FUSED prep — transpose (blocks 0..4095) + weight repack (4096..)
// Vectorized loads (2x float4) and stores (uint4 = 8 bf16 ch).
// ---------------------------------------------------------------------------
__global__ __launch_bounds__(256) void prep_kernel(
    const float* __restrict__ x,
    const float* __restrict__ wm, const float* __restrict__ woff,
    const float* __restrict__ wmask,
    ushort_t* __restrict__ xt, ushort_t* __restrict__ wt,
    ushort_t* __restrict__ wb)
{
    __shared__ float tile[64][33];
    int bid = blockIdx.x;
    int t   = threadIdx.x;

    if (bid < 4096) {
        // ---- transpose: NCHW fp32 -> NHWC bf16 ----
        int bh = bid >> 2;
        int w0 = (bid & 3) * 32;
        int b  = bh >> 7;
        int h  = bh & 127;

        {
            int c  = t >> 2;
            int wq = t & 3;
            const float* src = x + (((size_t)(b*CC + c))*HH + h)*WW + (w0 + wq*8);
            float4 v0 = ((const float4*)src)[0];
            float4 v1 = ((const float4*)src)[1];
            int wbse = wq*8;
            tile[c][wbse+0] = v0.x; tile[c][wbse+1] = v0.y;
            tile[c][wbse+2] = v0.z; tile[c][wbse+3] = v0.w;
            tile[c][wbse+4] = v1.x; tile[c][wbse+5] = v1.y;
            tile[c][wbse+6] = v1.z; tile[c][wbse+7] = v1.w;
        }
        __syncthreads();
        {
            int w   = t & 31;
            int cg8 = t >> 5;
            unsigned uu[4];
            #pragma unroll
            for (int j = 0; j < 4; ++j)
                uu[j] = cvt_pk_bf16(tile[cg8*8 + 2*j][w], tile[cg8*8 + 2*j + 1][w]);
            *(uint4*)(xt + (((size_t)(b*HH + h))*WW + (w0 + w))*CC + cg8*8)
                = make_uint4(uu[0], uu[1], uu[2], uu[3]);
        }
    } else {
        // ---- weight repack to bf16 ----
        int i = (bid - 4096) * 256 + t;
        if (i < 36864) {
            int o = i / 576, k = i % 576, tap = k >> 6, c = k & 63;
            wt[i] = f2b(wm[o*576 + c*9 + tap]);
        }
        int j = i - 36864;
        if (j >= 0 && j < 18432) {
            int o = j / 576, k = j % 576, tap = k >> 6, c = k & 63;
            float v = 0.f;
            if (o < 18)      v = woff[o*576 + c*9 + tap];
            else if (o < 27) v = wmask[(o-18)*576 + c*9 + tap];
            wb[j] = f2b(v);
        }
    }
}

// ---------------------------------------------------------------------------
// Kernel 2: conv3x3 -> 18 offsets + 9 sigmoid masks (r5 form, 16x16 tiles).
// ---------------------------------------------------------------------------
__global__ __launch_bounds__(256) void conv27_kernel(
    const ushort_t* __restrict__ xt, const ushort_t* __restrict__ wb,
    const float* __restrict__ boff, const float* __restrict__ bmsk,
    float* __restrict__ om)
{
    __shared__ ushort_t win[18*18*72];
    int bid = blockIdx.x;
    int b  = bid >> 6;
    int th = (bid >> 3) & 7;
    int tw = bid & 7;
    int h0 = th * 16, w0 = tw * 16;
    int t = threadIdx.x;

    for (int idx = t; idx < 18*18*8; idx += 256) {
        int r   = idx / 144;
        int rem = idx - r*144;
        int col = rem >> 3;
        int ch  = (rem & 7) << 3;
        int y = h0 + r - 1, x = w0 + col - 1;
        uint4 val = make_uint4(0,0,0,0);
        if ((unsigned)y < (unsigned)HH && (unsigned)x < (unsigned)WW)
            val = *(const uint4*)(xt + ((((size_t)b*HH + y)*WW + x) << 6) + ch);
        *(uint4*)(win + (r*18 + col)*72 + ch) = val;
    }
    __syncthreads();

    int lane = t & 63, wv = t >> 6;
    int n = lane & 15, quad = lane >> 4;
    const ushort_t* wb0 = wb + n*576;
    const ushort_t* wb1 = wb + (16 + n)*576;

    floatx4 acc0[4], acc1[4];
    #pragma unroll
    for (int mt = 0; mt < 4; ++mt) {
        acc0[mt] = (floatx4){0.f,0.f,0.f,0.f};
        acc1[mt] = (floatx4){0.f,0.f,0.f,0.f};
    }

    #pragma unroll
    for (int s = 0; s < 18; ++s) {
        int tap  = s >> 1;
        int tr   = tap / 3, tc = tap % 3;
        int coff = (s & 1)*32 + quad*8;
        int kk = tap*64 + coff;
        bf16x8 b0 = *(const bf16x8*)(wb0 + kk);
        bf16x8 b1 = *(const bf16x8*)(wb1 + kk);
        #pragma unroll
        for (int mt = 0; mt < 4; ++mt) {
            int ty = wv*4 + mt;
            bf16x8 a = *(const bf16x8*)(win + ((ty + tr)*18 + (n + tc))*72 + coff);
            acc0[mt] = __builtin_amdgcn_mfma_f32_16x16x32_bf16(a, b0, acc0[mt], 0, 0, 0);
            acc1[mt] = __builtin_amdgcn_mfma_f32_16x16x32_bf16(a, b1, acc1[mt], 0, 0, 0);
        }
    }

    #pragma unroll
    for (int mt = 0; mt < 4; ++mt) {
        int ty = wv*4 + mt;
        #pragma unroll
        for (int r = 0; r < 4; ++r) {
            int tx = quad*4 + r;
            size_t p = ((size_t)(b*HH + h0 + ty))*WW + (w0 + tx);
            float* dst = om + p*28;
            dst[n] = acc0[mt][r] + boff[n];
            int o1 = 16 + n;
            if (o1 < 18) {
                dst[o1] = acc1[mt][r] + boff[o1];
            } else if (o1 < 27) {
                float z = acc1[mt][r] + bmsk[o1 - 18];
                dst[o1] = 1.f / (1.f + expf(-z));
            } else if (o1 == 27) {
                dst[27] = 0.f;
            }
        }
    }
}

// ---------------------------------------------------------------------------
// Deform helpers: issue one tap's 8 gathers + weights; pack one tap to LDS.
// Plain forceinline functions (no lambda); all array indices compile-time
// after unrolling -> registers (rule-#20-safe). Depth-1 pipeline = 16 uint4.
// ---------------------------------------------------------------------------
__device__ __forceinline__ void issue_tap(
    uint4* q, float* cw,
    const ushort_t* xbase, int cg, int h_a, int w_a,
    int kr, int kc, float dy, float dx, float m)
{
    float py = (float)(h_a + kr - 1) + dy;
    float px = (float)(w_a + kc - 1) + dx;
    float y0f = floorf(py), x0f = floorf(px);
    float ly = py - y0f, lx = px - x0f;
    int y0 = (int)y0f, x0 = (int)x0f, y1 = y0 + 1, x1 = x0 + 1;
    float vy0 = ((unsigned)y0 < (unsigned)HH) ? 1.f : 0.f;
    float vy1 = ((unsigned)y1 < (unsigned)HH) ? 1.f : 0.f;
    float vx0 = ((unsigned)x0 < (unsigned)WW) ? 1.f : 0.f;
    float vx1 = ((unsigned)x1 < (unsigned)WW) ? 1.f : 0.f;
    cw[0] = (1.f-ly)*(1.f-lx)*vy0*vx0*m;
    cw[1] = (1.f-ly)*lx      *vy0*vx1*m;
    cw[2] = ly*(1.f-lx)      *vy1*vx0*m;
    cw[3] = ly*lx            *vy1*vx1*m;
    int ys[4] = { y0, y0, y1, y1 };
    int xs[4] = { x0, x1, x0, x1 };
    #pragma unroll
    for (int cn = 0; cn < 4; ++cn) {
        int yc = min(max(ys[cn], 0), HH-1);
        int xc = min(max(xs[cn], 0), WW-1);
        const uint4* cp = (const uint4*)(xbase + (((yc << 7) + xc) << 6) + cg*16);
        q[2*cn]   = cp[0];
        q[2*cn+1] = cp[1];
    }
}

__device__ __forceinline__ void pack_tap(
    const uint4* q, const float* cw, ushort_t* dst)
{
    f32x2 v2[8];
    {
        f32x2 w2; w2.x = cw[0]; w2.y = cw[0];
        unsigned u0[8] = { q[0].x, q[0].y, q[0].z, q[0].w,
                           q[1].x, q[1].y, q[1].z, q[1].w };
        #pragma unroll
        for (int j = 0; j < 8; ++j) {
            f32x2 f;
            f.x = __uint_as_float(u0[j] << 16);
            f.y = __uint_as_float(u0[j] & 0xffff0000u);
            v2[j] = pk_mul(f, w2);
        }
    }
    #pragma unroll
    for (int cn = 1; cn < 4; ++cn) {
        f32x2 w2; w2.x = cw[cn]; w2.y = cw[cn];
        unsigned u0[8] = { q[2*cn].x,   q[2*cn].y,   q[2*cn].z,   q[2*cn].w,
                           q[2*cn+1].x, q[2*cn+1].y, q[2*cn+1].z, q[2*cn+1].w };
        #pragma unroll
        for (int j = 0; j < 8; ++j) {
            f32x2 f;
            f.x = __uint_as_float(u0[j] << 16);
            f.y = __uint_as_float(u0[j] & 0xffff0000u);
            v2[j] = pk_fma(f, w2, v2[j]);
        }
    }
    unsigned uu[8];
    #pragma unroll
    for (int j = 0; j < 8; ++j)
        uu[j] = cvt_pk_bf16(v2[j].x, v2[j].y);
    uint4* d = (uint4*)dst;
    d[0] = make_uint4(uu[0], uu[1], uu[2], uu[3]);
    d[1] = make_uint4(uu[4], uu[5], uu[6], uu[7]);
}

// ---------------------------------------------------------------------------
// Kernel 3: deformable sampling + bf16 MFMA GEMM — 3-tap phased, depth-1
// tap pipeline. Tap g+1's 8 gathers are issued BEFORE packing tap g, so
// pack waits only on tap g's loads (counted vmcnt) while g+1's remain in
// flight; at phase boundaries they ride across the barrier + MFMA block.
// r11's depth-3 version spilled q[24] to scratch (WRITE_SIZE 32->103MB);
// depth-1 with q[2][8], all indices compile-time, stays in registers.
// ---------------------------------------------------------------------------
#define SROW 200   // ushorts per pixel row: 3 taps * 64 ch + 8 pad

__global__ __launch_bounds__(256, 3) void deform_kernel(
    const ushort_t* __restrict__ xt, const float* __restrict__ om,
    const ushort_t* __restrict__ wt, float* __restrict__ out)
{
    __shared__ ushort_t samp[64*SROW];   // 25600 B, single-buffered

    int t = threadIdx.x;
    int lane = t & 63, wv = t >> 6;
    int bid = blockIdx.x;
    int b  = bid >> 8;
    int th = (bid >> 4) & 15;
    int tw = bid & 15;
    int h0 = th * 8, w0 = tw * 8;

    // sampling role: 4 threads/pixel, 16 ch each; 8x8 pixel tile
    int pa = t >> 2, cg = t & 3;
    int ph = pa >> 3, pw = pa & 7;
    int h_a = h0 + ph, w_a = w0 + pw;
    const float* omp = om + (((size_t)(b*HH + h_a))*WW + w_a) * 28;
    const ushort_t* xbase = xt + ((size_t)b << 20);

    // MFMA role
    int n = lane & 15, quad = lane >> 4;
    floatx4 acc[4];
    #pragma unroll
    for (int i = 0; i < 4; ++i) acc[i] = (floatx4){0.f,0.f,0.f,0.f};
    const ushort_t* wrow = wt + (wv*16 + n)*576 + quad*8;

    uint4 q[2][8];     // depth-1 double buffer, compile-time indexed
    float cw[2][4];

    // params for phase 0; issue tap 0
    float dyv[3], dxv[3], mv[3];
    #pragma unroll
    for (int j = 0; j < 3; ++j) {
        dyv[j] = omp[2*j]; dxv[j] = omp[2*j+1]; mv[j] = omp[18+j];
    }
    issue_tap(q[0], cw[0], xbase, cg, h_a, w_a, 0, 0, dyv[0], dxv[0], mv[0]);

    #pragma unroll
    for (int p = 0; p < 3; ++p) {
        // this phase's 6 weight B-frags
        bf16x8 wf[6];
        #pragma unroll
        for (int s = 0; s < 6; ++s)
            wf[s] = *(const bf16x8*)(wrow + (p*6 + s)*32);   // tap*64+half*32

        // next phase's params (needed to issue its first tap early)
        float dyn_[3], dxn_[3], mn_[3];
        if (p < 2) {
            #pragma unroll
            for (int j = 0; j < 3; ++j) {
                int k2 = 3*(p+1) + j;
                dyn_[j] = omp[2*k2]; dxn_[j] = omp[2*k2+1]; mn_[j] = omp[18+k2];
            }
        }

        // ---- phase A: for each tap, issue NEXT tap's gathers, then pack ----
        #pragma unroll
        for (int kk = 0; kk < 3; ++kk) {
            int g = 3*p + kk;                  // global tap index (constant)
            if (g < 8) {
                if (kk < 2)
                    issue_tap(q[(g+1)&1], cw[(g+1)&1], xbase, cg, h_a, w_a,
                              p, kk+1, dyv[kk+1], dxv[kk+1], mv[kk+1]);
                else
                    issue_tap(q[(g+1)&1], cw[(g+1)&1], xbase, cg, h_a, w_a,
                              p+1, 0, dyn_[0], dxn_[0], mn_[0]);
            }
            // pack tap g (counted vmcnt: waits g's 8 loads, leaves g+1's)
            pack_tap(q[g&1], cw[g&1], samp + pa*SROW + kk*64 + cg*16);
        }

        __syncthreads();          // RAW: samp ready

        // ---------------- phase B: 24 MFMAs from LDS + reg weights ----------
        __builtin_amdgcn_s_setprio(1);
        #pragma unroll
        for (int kk = 0; kk < 3; ++kk) {
            #pragma unroll
            for (int half = 0; half < 2; ++half) {
                bf16x8 bfrag = wf[kk*2 + half];
                #pragma unroll
                for (int mt = 0; mt < 4; ++mt) {
                    bf16x8 afrag = *(const bf16x8*)(samp + (mt*16 + n)*SROW
                                                    + kk*64 + half*32 + quad*8);
                    acc[mt] = __builtin_amdgcn_mfma_f32_16x16x32_bf16(
                                  afrag, bfrag, acc[mt], 0, 0, 0);
                }
            }
        }
        __builtin_amdgcn_s_setprio(0);

        if (p < 2) {
            __syncthreads();      // WAR: next phase overwrites samp
            #pragma unroll
            for (int j = 0; j < 3; ++j) {
                dyv[j] = dyn_[j]; dxv[j] = dxn_[j]; mv[j] = mn_[j];
            }
        }
    }

    // store: out[b][o][h][w], o = wv*16 + n; D rows = local pixel id
    // p_local = mt*16 + quad*4 + r -> row = h0 + mt*2 + (quad>>1),
    //                                  col = w0 + (quad&1)*4 + r
    float* op = out + ((size_t)b*OO + (wv*16 + n))*HW;
    #pragma unroll
    for (int mt = 0; mt < 4; ++mt) {
        int row = h0 + mt*2 + (quad >> 1);
        int col = w0 + (quad & 1)*4;
        float4 st = make_float4(acc[mt][0], acc[mt][1], acc[mt][2], acc[mt][3]);
        *(float4*)(op + row*WW + col) = st;
    }
}

// ---------------------------------------------------------------------------
extern "C" void kernel_launch(void* const* d_in, const int* in_sizes, int n_in,
                              void* d_out, int out_size, void* d_ws, size_t ws_size,
                              hipStream_t stream)
{
    const float* x      = (const float*)d_in[0];
    const float* w_main = (const float*)d_in[1];
    const float* w_off  = (const float*)d_in[2];
    const float* b_off  = (const float*)d_in[3];
    const float* w_msk  = (const float*)d_in[4];
    const float* b_msk  = (const float*)d_in[5];
    float* out = (float*)d_out;

    unsigned char* ws = (unsigned char*)d_ws;
    ushort_t* xt = (ushort_t*)ws;
    float*    om = (float*)(ws + XT_BYTES);
    ushort_t* wt = (ushort_t*)(ws + XT_BYTES + OM_BYTES);
    ushort_t* wb = (ushort_t*)(ws + XT_BYTES + OM_BYTES + WT_BYTES);

    // K1: transpose (4096 blocks) + repack (216 blocks) fused
    prep_kernel<<<4096 + 216, 256, 0, stream>>>(x, w_main, w_off, w_msk, xt, wt, wb);

    // K2: conv27 (r5 form, own occupancy)
    conv27_kernel<<<NPIX/256, 256, 0, stream>>>(xt, wb, b_off, b_msk, om);

    // K3: deform, 3-tap phased + depth-1 tap pipeline
    deform_kernel<<<NPIX/64, 256, 0, stream>>>(xt, om, wt, out);
}